// Round 13
// baseline (112.404 us; speedup 1.0000x reference)
//
#include <hip/hip_runtime.h>

#define M_ROWS 16384
#define DIMX   1024
#define CD     12
#define KCB    4096
#define PADW   60   // padded dwords per float4-position fragment (48 data + 12 pad)
#define NSLAB  512  // one hist slab per k_body block

// ---------- Kernel A: h = x @ W_in + b_in ; writes h and oidx ----------
// 512 threads (8 waves; round-12 lesson: 512-thread blocks get a 128-VGPR
// budget). Each wave sweeps 4 ROWS per W-pass (2 sweeps = 8 rows) -> halves
// LDS read traffic vs the 2-row version and doubles resident waves (16/CU).
// Per-row arithmetic (FMA order k,e,d; butterfly ofs 1..32; +bin at end) is
// operation-for-operation identical to the round-1..11 version => exact indices.
__global__ __launch_bounds__(512) void k_hproj(
    const float* __restrict__ x, const float* __restrict__ Win,
    const float* __restrict__ bin, float* __restrict__ h, float* __restrict__ oidx)
{
  __shared__ __align__(16) float w[256 * PADW];   // 60 KB
  for (int f = threadIdx.x; f < 256 * 12; f += 512) {
    const int P = f / 12, c = f % 12;
    float4 v = reinterpret_cast<const float4*>(Win)[f];
    *reinterpret_cast<float4*>(&w[P * PADW + 4 * c]) = v;
  }
  __syncthreads();

  const int wave = threadIdx.x >> 6;
  const int lane = threadIdx.x & 63;

  for (int sweep = 0; sweep < 2; ++sweep) {
    const int row0 = blockIdx.x * 64 + wave * 8 + sweep * 4;
    const float4* xr0 = reinterpret_cast<const float4*>(x + (size_t)row0 * DIMX);
    const float4* xr1 = reinterpret_cast<const float4*>(x + (size_t)(row0 + 1) * DIMX);
    const float4* xr2 = reinterpret_cast<const float4*>(x + (size_t)(row0 + 2) * DIMX);
    const float4* xr3 = reinterpret_cast<const float4*>(x + (size_t)(row0 + 3) * DIMX);

    float a0[CD], a1[CD], a2[CD], a3[CD];
#pragma unroll
    for (int d = 0; d < CD; ++d) { a0[d]=0.f; a1[d]=0.f; a2[d]=0.f; a3[d]=0.f; }

#pragma unroll
    for (int k = 0; k < 4; ++k) {
      const int P = lane + 64 * k;
      float4 xv0 = xr0[P];
      float4 xv1 = xr1[P];
      float4 xv2 = xr2[P];
      float4 xv3 = xr3[P];
      const float4* wf = reinterpret_cast<const float4*>(&w[P * PADW]);
      float4 wq[12];
#pragma unroll
      for (int c = 0; c < 12; ++c) wq[c] = wf[c];
      const float* wfl = reinterpret_cast<const float*>(wq);
      float xe0[4] = {xv0.x, xv0.y, xv0.z, xv0.w};
      float xe1[4] = {xv1.x, xv1.y, xv1.z, xv1.w};
      float xe2[4] = {xv2.x, xv2.y, xv2.z, xv2.w};
      float xe3[4] = {xv3.x, xv3.y, xv3.z, xv3.w};
#pragma unroll
      for (int e = 0; e < 4; ++e)
#pragma unroll
        for (int d = 0; d < CD; ++d) {
          const float wv = wfl[e * CD + d];
          a0[d] = fmaf(xe0[e], wv, a0[d]);
          a1[d] = fmaf(xe1[e], wv, a1[d]);
          a2[d] = fmaf(xe2[e], wv, a2[d]);
          a3[d] = fmaf(xe3[e], wv, a3[d]);
        }
    }
#pragma unroll
    for (int ofs = 1; ofs < 64; ofs <<= 1)
#pragma unroll
      for (int d = 0; d < CD; ++d) {
        a0[d] += __shfl_xor(a0[d], ofs, 64);
        a1[d] += __shfl_xor(a1[d], ofs, 64);
        a2[d] += __shfl_xor(a2[d], ofs, 64);
        a3[d] += __shfl_xor(a3[d], ofs, 64);
      }

    if (lane == 0) {
      int i0 = 0, i1 = 0, i2 = 0, i3 = 0;
#pragma unroll
      for (int d = 0; d < CD; ++d) {
        const float bd = bin[d];
        const float h0 = a0[d] + bd;
        const float h1 = a1[d] + bd;
        const float h2 = a2[d] + bd;
        const float h3 = a3[d] + bd;
        h[(size_t)row0 * CD + d]       = h0;
        h[(size_t)(row0 + 1) * CD + d] = h1;
        h[(size_t)(row0 + 2) * CD + d] = h2;
        h[(size_t)(row0 + 3) * CD + d] = h3;
        i0 |= (h0 > 0.f) ? (1 << d) : 0;
        i1 |= (h1 > 0.f) ? (1 << d) : 0;
        i2 |= (h2 > 0.f) ? (1 << d) : 0;
        i3 |= (h3 > 0.f) ? (1 << d) : 0;
      }
      oidx[row0]     = (float)i0;
      oidx[row0 + 1] = (float)i1;
      oidx[row0 + 2] = (float)i2;
      oidx[row0 + 3] = (float)i3;
    }
  }
}

// ---------- Kernel B: fused out-projection + entropy/commit + histogram ----------
// Round-11 proven version (33 us): 512 threads, 32 rows per block; fire-and-
// forget tail, now plain scal_part stores (no atomics anywhere, no pre-zero).
__global__ __launch_bounds__(512) void k_body(
    const float* __restrict__ h, const float* __restrict__ Wout,
    const float* __restrict__ bout, const float* __restrict__ oidx,
    float* __restrict__ out, float* __restrict__ hist_part,
    float* __restrict__ scal_part)
{
  __shared__ __align__(16) float sq[32 * 16];    // q[row][d], row-padded to 16
  __shared__ float pp[8], cc[8];
  const int t    = threadIdx.x;          // 0..511
  const int bid  = blockIdx.x;
  const int row0 = bid * 32;

  // ---------------- Phase 0: q-tree once per block ----------------
  if (t < 384) {                          // waves 0..5, one (row,d) per thread
    const float hv  = h[(size_t)row0 * CD + t];   // coalesced 384 floats
    const float ax  = fabsf(40.f * hv);
    const float e2  = __expf(-ax);
    const float s1  = 1.f + e2;
    const float inv = 1.f / s1;
    const float qv  = (hv > 0.f) ? inv : e2 * inv;          // sigmoid(40 h)
    sq[(t / 12) * 16 + (t % 12)] = qv;
    float pse_c = __logf(s1) + ax * e2 * inv;               // per-dim entropy
    const float dd = fabsf(hv) - 1.f;
    float com_c = dd * dd;
#pragma unroll
    for (int ofs = 1; ofs < 64; ofs <<= 1) {
      pse_c += __shfl_xor(pse_c, ofs, 64);
      com_c += __shfl_xor(com_c, ofs, 64);
    }
    if ((t & 63) == 0) { pp[t >> 6] = pse_c; cc[t >> 6] = com_c; }
  }

  // ---------------- Phase A: out = sign(h) @ W_out + b_out ----------------
  {
    float w0[CD], w1[CD];
#pragma unroll
    for (int d = 0; d < CD; ++d) {
      float2 v = *reinterpret_cast<const float2*>(Wout + d * DIMX + 2 * t);
      w0[d] = v.x; w1[d] = v.y;
    }
    const float2 b2 = *reinterpret_cast<const float2*>(bout + 2 * t);

    for (int i = 0; i < 32; ++i) {
      const int row = row0 + i;
      const int idx = (int)oidx[row];    // block-uniform scalar load
      float o0 = b2.x, o1 = b2.y;
#pragma unroll
      for (int d = 0; d < CD; ++d) {
        const float s = ((idx >> d) & 1) ? 1.f : -1.f;
        o0 = fmaf(s, w0[d], o0);
        o1 = fmaf(s, w1[d], o1);
      }
      *reinterpret_cast<float2*>(out + (size_t)row * DIMX + 2 * t) = make_float2(o0, o1);
    }
  }

  __syncthreads();                        // sq + pp/cc ready for all waves

  // ---------------- Phase B: factorized histogram ----------------
  const int lane = t & 63;
  const int w8   = t >> 6;                // wave id 0..7; m in [8*w8, 8*w8+8)

  float c0=0.f,c1=0.f,c2=0.f,c3=0.f,c4=0.f,c5=0.f,c6=0.f,c7=0.f;

  for (int i = 0; i < 32; ++i) {
    const float4 qa = *reinterpret_cast<const float4*>(&sq[i * 16]);      // q0..q3
    const float4 qb = *reinterpret_cast<const float4*>(&sq[i * 16 + 4]);  // q4..q7
    const float4 qc = *reinterpret_cast<const float4*>(&sq[i * 16 + 8]);  // q8..q11

    float A = ((lane >> 0) & 1) ? qa.x : 1.f - qa.x;
    A      *= ((lane >> 1) & 1) ? qa.y : 1.f - qa.y;
    A      *= ((lane >> 2) & 1) ? qa.z : 1.f - qa.z;
    A      *= ((lane >> 3) & 1) ? qa.w : 1.f - qa.w;
    A      *= ((lane >> 4) & 1) ? qb.x : 1.f - qb.x;
    A      *= ((lane >> 5) & 1) ? qb.y : 1.f - qb.y;

    const float t6 = 1.f - qb.z, t7 = 1.f - qb.w, t8 = 1.f - qc.x;
    const float u0 = t6 * t7, u1 = qb.z * t7, u2 = t6 * qb.w, u3 = qb.z * qb.w;
    const float E0 = A * (u0 * t8),   E1 = A * (u1 * t8),   E2 = A * (u2 * t8),   E3 = A * (u3 * t8);
    const float E4 = A * (u0 * qc.x), E5 = A * (u1 * qc.x), E6 = A * (u2 * qc.x), E7 = A * (u3 * qc.x);

    const float vw = (((w8 & 1) ? qc.y : 1.f - qc.y) * ((w8 & 2) ? qc.z : 1.f - qc.z));
    const float Dw = vw * ((w8 & 4) ? qc.w : 1.f - qc.w);

    c0 = fmaf(E0, Dw, c0); c1 = fmaf(E1, Dw, c1); c2 = fmaf(E2, Dw, c2); c3 = fmaf(E3, Dw, c3);
    c4 = fmaf(E4, Dw, c4); c5 = fmaf(E5, Dw, c5); c6 = fmaf(E6, Dw, c6); c7 = fmaf(E7, Dw, c7);
  }

  // disjoint coalesced slab write: index = (8*w8 + e)*64 + lane
  float* hp = hist_part + (size_t)bid * KCB + (size_t)w8 * 512 + lane;
  hp[0*64] = c0; hp[1*64] = c1; hp[2*64] = c2; hp[3*64] = c3;
  hp[4*64] = c4; hp[5*64] = c5; hp[6*64] = c6; hp[7*64] = c7;

  // tail: plain per-block partial stores (no atomics, nothing pre-zeroed)
  if (t == 0) {
    scal_part[bid * 2]     = pp[0] + pp[1] + pp[2] + pp[3] + pp[4] + pp[5];
    scal_part[bid * 2 + 1] = cc[0] + cc[1] + cc[2] + cc[3] + cc[4] + cc[5];
  }
}

// ---------- Kernel C: stage-1 slab reduction (128 blocks) ----------
__global__ __launch_bounds__(256) void k_hr1(
    const float* __restrict__ hist_part, float* __restrict__ part2)
{
  const int j0    = (blockIdx.x & 7) * 512 + threadIdx.x;
  const int chunk = blockIdx.x >> 3;              // 0..15
  const int s0    = chunk * (NSLAB / 16);
  float acc0 = 0.f, acc1 = 0.f;
#pragma unroll 4
  for (int s = 0; s < NSLAB / 16; ++s) {
    const float* hp = hist_part + (size_t)(s0 + s) * KCB;
    acc0 += hp[j0];
    acc1 += hp[j0 + 256];
  }
  part2[(size_t)chunk * KCB + j0]       = acc0;
  part2[(size_t)chunk * KCB + j0 + 256] = acc1;
}

// ---------- Kernel D: final entropy + scalar partials -> aux (1 block) ----------
__global__ __launch_bounds__(256) void k_fin(
    const float* __restrict__ part2, const float* __restrict__ scal_part,
    float* __restrict__ aux)
{
  const int t = threadIdx.x;
  float term = 0.f;
#pragma unroll
  for (int k = 0; k < 16; ++k) {
    const int j = t + 256 * k;
    float a = 0.f;
#pragma unroll
    for (int c = 0; c < 16; ++c) a += part2[(size_t)c * KCB + j];
    a *= (1.f / 16384.f);
    term -= a * __logf(a + 1e-10f);
  }
  // pse/com partials: 512 blocks x {pse, com}
  const float2 s0 = *reinterpret_cast<const float2*>(&scal_part[2 * t]);
  const float2 s1 = *reinterpret_cast<const float2*>(&scal_part[2 * (t + 256)]);
  float ps = s0.x + s1.x;
  float cs = s0.y + s1.y;
#pragma unroll
  for (int ofs = 1; ofs < 64; ofs <<= 1) {
    term += __shfl_xor(term, ofs, 64);
    ps   += __shfl_xor(ps,   ofs, 64);
    cs   += __shfl_xor(cs,   ofs, 64);
  }
  __shared__ float sw[4], sp[4], sc[4];
  if ((t & 63) == 0) { sw[t >> 6] = term; sp[t >> 6] = ps; sc[t >> 6] = cs; }
  __syncthreads();
  if (t == 0) {
    const float cbe = sw[0] + sw[1] + sw[2] + sw[3];
    const float PS  = sp[0] + sp[1] + sp[2] + sp[3];
    const float CS  = sc[0] + sc[1] + sc[2] + sc[3];
    aux[0] = PS * (1.f / 16384.f) - cbe + CS * (1.f / 196608.f);
  }
}

extern "C" void kernel_launch(void* const* d_in, const int* in_sizes, int n_in,
                              void* d_out, int out_size, void* d_ws, size_t ws_size,
                              hipStream_t stream)
{
  const float* x    = (const float*)d_in[0];
  const float* Win  = (const float*)d_in[1];
  const float* bin  = (const float*)d_in[2];
  const float* Wout = (const float*)d_in[3];
  const float* bout = (const float*)d_in[4];

  float* out  = (float*)d_out;                       // [16384 x 1024]
  float* oidx = out + (size_t)M_ROWS * DIMX;         // [16384]
  float* aux  = oidx + M_ROWS;                       // [1]

  float* ws        = (float*)d_ws;
  float* h         = ws;                             // 196608 floats
  float* scal_part = ws + (size_t)M_ROWS * CD;       // 1024 floats
  float* part2     = scal_part + 1024;               // 16 * 4096 floats
  float* hist_part = part2 + 16 * KCB;               // NSLAB * 4096 floats

  k_hproj<<<M_ROWS / 64, 512, 0, stream>>>(x, Win, bin, h, oidx);
  k_body <<<NSLAB, 512, 0, stream>>>(h, Wout, bout, oidx, out, hist_part, scal_part);
  k_hr1  <<<128, 256, 0, stream>>>(hist_part, part2);
  k_fin  <<<1, 256, 0, stream>>>(part2, scal_part, aux);
}

// Round 14
// 63.950 us; speedup vs baseline: 1.7577x; 1.7577x over previous
//
#include <hip/hip_runtime.h>

#define M_ROWS 16384
#define DIMX   1024
#define CD     12
#define KCB    4096
#define PADW   52   // 48 data + 4 pad dwords: 53.25 KB LDS -> 3 blocks/CU;
                    // stride 52 dwords => start banks {0,20,8,28,16,4,24,12}
                    // per 8 lanes, each b128 = 4 consecutive banks => conflict-free
#define NSLAB  512  // one hist slab per k_body block

// ---------- Kernel A: h = x @ W_in + b_in ; writes h and oidx ----------
// Round-11 proven 256-thread 2-row structure (round-13 lesson: 4-row spills).
// Per-row arithmetic (FMA order k,e,d; butterfly ofs 1..32; +bin at end) is
// bit-identical to the round-1..11 version => exact index match.
__global__ __launch_bounds__(256, 2) void k_hproj(
    const float* __restrict__ x, const float* __restrict__ Win,
    const float* __restrict__ bin, float* __restrict__ h, float* __restrict__ oidx)
{
  __shared__ __align__(16) float w[256 * PADW];   // 53.25 KB
  for (int f = threadIdx.x; f < 256 * 12; f += 256) {
    const int P = f / 12, c = f % 12;
    float4 v = reinterpret_cast<const float4*>(Win)[f];
    *reinterpret_cast<float4*>(&w[P * PADW + 4 * c]) = v;
  }
  __syncthreads();

  const int wave = threadIdx.x >> 6;
  const int lane = threadIdx.x & 63;
  const int g    = blockIdx.x * 4 + wave;         // 8 rows per wave

  float bb[CD];
#pragma unroll
  for (int d = 0; d < CD; ++d) bb[d] = bin[d];

  for (int it = 0; it < 4; ++it) {                // 2 rows per iteration
    const int row0 = g * 8 + it * 2;
    const float4* xr0 = reinterpret_cast<const float4*>(x + (size_t)row0 * DIMX);
    const float4* xr1 = reinterpret_cast<const float4*>(x + (size_t)(row0 + 1) * DIMX);
    float a0[CD], a1[CD];
#pragma unroll
    for (int d = 0; d < CD; ++d) { a0[d] = 0.f; a1[d] = 0.f; }

#pragma unroll
    for (int k = 0; k < 4; ++k) {
      const int P = lane + 64 * k;
      float4 xv0 = xr0[P];
      float4 xv1 = xr1[P];
      const float4* wf = reinterpret_cast<const float4*>(&w[P * PADW]);
      float4 wq[12];
#pragma unroll
      for (int c = 0; c < 12; ++c) wq[c] = wf[c];
      const float* wfl = reinterpret_cast<const float*>(wq);
      float xe0[4] = {xv0.x, xv0.y, xv0.z, xv0.w};
      float xe1[4] = {xv1.x, xv1.y, xv1.z, xv1.w};
#pragma unroll
      for (int e = 0; e < 4; ++e)
#pragma unroll
        for (int d = 0; d < CD; ++d) {
          const float wv = wfl[e * CD + d];
          a0[d] = fmaf(xe0[e], wv, a0[d]);
          a1[d] = fmaf(xe1[e], wv, a1[d]);
        }
    }
#pragma unroll
    for (int ofs = 1; ofs < 64; ofs <<= 1)
#pragma unroll
      for (int d = 0; d < CD; ++d) {
        a0[d] += __shfl_xor(a0[d], ofs, 64);
        a1[d] += __shfl_xor(a1[d], ofs, 64);
      }

    if (lane == 0) {
      int i0 = 0, i1 = 0;
#pragma unroll
      for (int d = 0; d < CD; ++d) {
        const float h0 = a0[d] + bb[d];
        const float h1 = a1[d] + bb[d];
        h[(size_t)row0 * CD + d]       = h0;
        h[(size_t)(row0 + 1) * CD + d] = h1;
        i0 |= (h0 > 0.f) ? (1 << d) : 0;
        i1 |= (h1 > 0.f) ? (1 << d) : 0;
      }
      oidx[row0]     = (float)i0;
      oidx[row0 + 1] = (float)i1;
    }
  }
}

// ---------- Kernel B: fused out-projection + entropy/commit + histogram ----------
// 512 threads, 32 rows per block. Phase 0: q once -> LDS. Then ONE per-row loop
// doing out-write AND hist accumulation (mixes store-bound + VALU-bound work;
// single barrier). Tail: plain scal_part stores (no atomics, no pre-zero).
__global__ __launch_bounds__(512) void k_body(
    const float* __restrict__ h, const float* __restrict__ Wout,
    const float* __restrict__ bout, const float* __restrict__ oidx,
    float* __restrict__ out, float* __restrict__ hist_part,
    float* __restrict__ scal_part)
{
  __shared__ __align__(16) float sq[32 * 16];    // q[row][d], row-padded to 16
  __shared__ float pp[8], cc[8];
  const int t    = threadIdx.x;          // 0..511
  const int bid  = blockIdx.x;
  const int row0 = bid * 32;

  // ---------------- Phase 0: q-tree once per block ----------------
  if (t < 384) {                          // waves 0..5, one (row,d) per thread
    const float hv  = h[(size_t)row0 * CD + t];   // coalesced 384 floats
    const float ax  = fabsf(40.f * hv);
    const float e2  = __expf(-ax);
    const float s1  = 1.f + e2;
    const float inv = 1.f / s1;
    const float qv  = (hv > 0.f) ? inv : e2 * inv;          // sigmoid(40 h)
    sq[(t / 12) * 16 + (t % 12)] = qv;
    float pse_c = __logf(s1) + ax * e2 * inv;               // per-dim entropy
    const float dd = fabsf(hv) - 1.f;
    float com_c = dd * dd;
#pragma unroll
    for (int ofs = 1; ofs < 64; ofs <<= 1) {
      pse_c += __shfl_xor(pse_c, ofs, 64);
      com_c += __shfl_xor(com_c, ofs, 64);
    }
    if ((t & 63) == 0) { pp[t >> 6] = pse_c; cc[t >> 6] = com_c; }
  }

  // W_out fragment + bias for phase A part of the fused loop
  float w0[CD], w1[CD];
#pragma unroll
  for (int d = 0; d < CD; ++d) {
    float2 v = *reinterpret_cast<const float2*>(Wout + d * DIMX + 2 * t);
    w0[d] = v.x; w1[d] = v.y;
  }
  const float2 b2 = *reinterpret_cast<const float2*>(bout + 2 * t);

  __syncthreads();                        // sq + pp/cc ready

  // ---------------- Fused per-row loop: out-write + histogram ----------------
  const int lane = t & 63;
  const int w8   = t >> 6;                // wave id 0..7; m in [8*w8, 8*w8+8)

  float c0=0.f,c1=0.f,c2=0.f,c3=0.f,c4=0.f,c5=0.f,c6=0.f,c7=0.f;

  for (int i = 0; i < 32; ++i) {
    const int row = row0 + i;

    // --- out row (store-bound) ---
    const int idx = (int)oidx[row];       // block-uniform scalar load
    float o0 = b2.x, o1 = b2.y;
#pragma unroll
    for (int d = 0; d < CD; ++d) {
      const float s = ((idx >> d) & 1) ? 1.f : -1.f;
      o0 = fmaf(s, w0[d], o0);
      o1 = fmaf(s, w1[d], o1);
    }
    *reinterpret_cast<float2*>(out + (size_t)row * DIMX + 2 * t) = make_float2(o0, o1);

    // --- histogram (VALU-bound, overlaps the store) ---
    const float4 qa = *reinterpret_cast<const float4*>(&sq[i * 16]);      // q0..q3
    const float4 qb = *reinterpret_cast<const float4*>(&sq[i * 16 + 4]);  // q4..q7
    const float4 qc = *reinterpret_cast<const float4*>(&sq[i * 16 + 8]);  // q8..q11

    float A = ((lane >> 0) & 1) ? qa.x : 1.f - qa.x;
    A      *= ((lane >> 1) & 1) ? qa.y : 1.f - qa.y;
    A      *= ((lane >> 2) & 1) ? qa.z : 1.f - qa.z;
    A      *= ((lane >> 3) & 1) ? qa.w : 1.f - qa.w;
    A      *= ((lane >> 4) & 1) ? qb.x : 1.f - qb.x;
    A      *= ((lane >> 5) & 1) ? qb.y : 1.f - qb.y;

    const float t6 = 1.f - qb.z, t7 = 1.f - qb.w, t8 = 1.f - qc.x;
    const float u0 = t6 * t7, u1 = qb.z * t7, u2 = t6 * qb.w, u3 = qb.z * qb.w;
    const float E0 = A * (u0 * t8),   E1 = A * (u1 * t8),   E2 = A * (u2 * t8),   E3 = A * (u3 * t8);
    const float E4 = A * (u0 * qc.x), E5 = A * (u1 * qc.x), E6 = A * (u2 * qc.x), E7 = A * (u3 * qc.x);

    const float vw = (((w8 & 1) ? qc.y : 1.f - qc.y) * ((w8 & 2) ? qc.z : 1.f - qc.z));
    const float Dw = vw * ((w8 & 4) ? qc.w : 1.f - qc.w);

    c0 = fmaf(E0, Dw, c0); c1 = fmaf(E1, Dw, c1); c2 = fmaf(E2, Dw, c2); c3 = fmaf(E3, Dw, c3);
    c4 = fmaf(E4, Dw, c4); c5 = fmaf(E5, Dw, c5); c6 = fmaf(E6, Dw, c6); c7 = fmaf(E7, Dw, c7);
  }

  // disjoint coalesced slab write: index = (8*w8 + e)*64 + lane
  float* hp = hist_part + (size_t)bid * KCB + (size_t)w8 * 512 + lane;
  hp[0*64] = c0; hp[1*64] = c1; hp[2*64] = c2; hp[3*64] = c3;
  hp[4*64] = c4; hp[5*64] = c5; hp[6*64] = c6; hp[7*64] = c7;

  // tail: plain per-block partial stores (no atomics, nothing pre-zeroed)
  if (t == 0) {
    scal_part[bid * 2]     = pp[0] + pp[1] + pp[2] + pp[3] + pp[4] + pp[5];
    scal_part[bid * 2 + 1] = cc[0] + cc[1] + cc[2] + cc[3] + cc[4] + cc[5];
  }
}

// ---------- Kernel C: stage-1 slab reduction (128 blocks) ----------
__global__ __launch_bounds__(256) void k_hr1(
    const float* __restrict__ hist_part, float* __restrict__ part2)
{
  const int j0    = (blockIdx.x & 7) * 512 + threadIdx.x;
  const int chunk = blockIdx.x >> 3;              // 0..15
  const int s0    = chunk * (NSLAB / 16);
  float acc0 = 0.f, acc1 = 0.f;
#pragma unroll 4
  for (int s = 0; s < NSLAB / 16; ++s) {
    const float* hp = hist_part + (size_t)(s0 + s) * KCB;
    acc0 += hp[j0];
    acc1 += hp[j0 + 256];
  }
  part2[(size_t)chunk * KCB + j0]       = acc0;
  part2[(size_t)chunk * KCB + j0 + 256] = acc1;
}

// ---------- Kernel D: final entropy + scalar partials -> aux (1 block) ----------
__global__ __launch_bounds__(256) void k_fin(
    const float* __restrict__ part2, const float* __restrict__ scal_part,
    float* __restrict__ aux)
{
  const int t = threadIdx.x;
  float term = 0.f;
#pragma unroll
  for (int k = 0; k < 16; ++k) {
    const int j = t + 256 * k;
    float a = 0.f;
#pragma unroll
    for (int c = 0; c < 16; ++c) a += part2[(size_t)c * KCB + j];
    a *= (1.f / 16384.f);
    term -= a * __logf(a + 1e-10f);
  }
  // pse/com partials: 512 blocks x {pse, com}
  const float2 s0 = *reinterpret_cast<const float2*>(&scal_part[2 * t]);
  const float2 s1 = *reinterpret_cast<const float2*>(&scal_part[2 * (t + 256)]);
  float ps = s0.x + s1.x;
  float cs = s0.y + s1.y;
#pragma unroll
  for (int ofs = 1; ofs < 64; ofs <<= 1) {
    term += __shfl_xor(term, ofs, 64);
    ps   += __shfl_xor(ps,   ofs, 64);
    cs   += __shfl_xor(cs,   ofs, 64);
  }
  __shared__ float sw[4], sp[4], sc[4];
  if ((t & 63) == 0) { sw[t >> 6] = term; sp[t >> 6] = ps; sc[t >> 6] = cs; }
  __syncthreads();
  if (t == 0) {
    const float cbe = sw[0] + sw[1] + sw[2] + sw[3];
    const float PS  = sp[0] + sp[1] + sp[2] + sp[3];
    const float CS  = sc[0] + sc[1] + sc[2] + sc[3];
    aux[0] = PS * (1.f / 16384.f) - cbe + CS * (1.f / 196608.f);
  }
}

extern "C" void kernel_launch(void* const* d_in, const int* in_sizes, int n_in,
                              void* d_out, int out_size, void* d_ws, size_t ws_size,
                              hipStream_t stream)
{
  const float* x    = (const float*)d_in[0];
  const float* Win  = (const float*)d_in[1];
  const float* bin  = (const float*)d_in[2];
  const float* Wout = (const float*)d_in[3];
  const float* bout = (const float*)d_in[4];

  float* out  = (float*)d_out;                       // [16384 x 1024]
  float* oidx = out + (size_t)M_ROWS * DIMX;         // [16384]
  float* aux  = oidx + M_ROWS;                       // [1]

  float* ws        = (float*)d_ws;
  float* h         = ws;                             // 196608 floats
  float* scal_part = ws + (size_t)M_ROWS * CD;       // 1024 floats
  float* part2     = scal_part + 1024;               // 16 * 4096 floats
  float* hist_part = part2 + 16 * KCB;               // NSLAB * 4096 floats

  k_hproj<<<512, 256, 0, stream>>>(x, Win, bin, h, oidx);
  k_body <<<NSLAB, 512, 0, stream>>>(h, Wout, bout, oidx, out, hist_part, scal_part);
  k_hr1  <<<128, 256, 0, stream>>>(hist_part, part2);
  k_fin  <<<1, 256, 0, stream>>>(part2, scal_part, aux);
}

// Round 15
// 62.784 us; speedup vs baseline: 1.7903x; 1.0186x over previous
//
#include <hip/hip_runtime.h>

#define M_ROWS 16384
#define DIMX   1024
#define CD     12
#define KCB    4096
#define PADW   52   // 48 data + 4 pad dwords: 53.25 KB LDS; 3 blocks/CU even at
                    // 512 threads (3*53248 = 159.75 KB <= 160 KB). Stride 52
                    // dwords => start banks {0,20,8,28,16,4,24,12} per 8 lanes,
                    // each b128 = 4 consecutive banks => conflict-free.
#define NSLAB  512  // one hist slab per k_body block

// ---------- Kernel A: h = x @ W_in + b_in ; writes h and oidx ----------
// 512 threads / 8 waves (round-15 change: 3 blocks/CU x 8 waves = 24 waves/CU =
// 6 waves/SIMD, 2x the 256-thread version's latency hiding). Each wave sweeps
// 8 rows, 2 per pass — per-row arithmetic (FMA order k,e,d; butterfly ofs
// 1..32; +bin at end) is bit-identical to the round-1..14 version => exact
// index match. ~80 live VGPRs < the 128 budget of 512-thread blocks (round-13's
// spill was the 4-row accumulator variant).
__global__ __launch_bounds__(512) void k_hproj(
    const float* __restrict__ x, const float* __restrict__ Win,
    const float* __restrict__ bin, float* __restrict__ h, float* __restrict__ oidx)
{
  __shared__ __align__(16) float w[256 * PADW];   // 53.25 KB
  for (int f = threadIdx.x; f < 256 * 12; f += 512) {
    const int P = f / 12, c = f % 12;
    float4 v = reinterpret_cast<const float4*>(Win)[f];
    *reinterpret_cast<float4*>(&w[P * PADW + 4 * c]) = v;
  }
  __syncthreads();

  const int wave = threadIdx.x >> 6;              // 0..7
  const int lane = threadIdx.x & 63;
  const int g    = blockIdx.x * 8 + wave;         // 8 rows per wave

  float bb[CD];
#pragma unroll
  for (int d = 0; d < CD; ++d) bb[d] = bin[d];

  for (int it = 0; it < 4; ++it) {                // 2 rows per iteration
    const int row0 = g * 8 + it * 2;
    const float4* xr0 = reinterpret_cast<const float4*>(x + (size_t)row0 * DIMX);
    const float4* xr1 = reinterpret_cast<const float4*>(x + (size_t)(row0 + 1) * DIMX);
    float a0[CD], a1[CD];
#pragma unroll
    for (int d = 0; d < CD; ++d) { a0[d] = 0.f; a1[d] = 0.f; }

#pragma unroll
    for (int k = 0; k < 4; ++k) {
      const int P = lane + 64 * k;
      float4 xv0 = xr0[P];
      float4 xv1 = xr1[P];
      const float4* wf = reinterpret_cast<const float4*>(&w[P * PADW]);
      float4 wq[12];
#pragma unroll
      for (int c = 0; c < 12; ++c) wq[c] = wf[c];
      const float* wfl = reinterpret_cast<const float*>(wq);
      float xe0[4] = {xv0.x, xv0.y, xv0.z, xv0.w};
      float xe1[4] = {xv1.x, xv1.y, xv1.z, xv1.w};
#pragma unroll
      for (int e = 0; e < 4; ++e)
#pragma unroll
        for (int d = 0; d < CD; ++d) {
          const float wv = wfl[e * CD + d];
          a0[d] = fmaf(xe0[e], wv, a0[d]);
          a1[d] = fmaf(xe1[e], wv, a1[d]);
        }
    }
#pragma unroll
    for (int ofs = 1; ofs < 64; ofs <<= 1)
#pragma unroll
      for (int d = 0; d < CD; ++d) {
        a0[d] += __shfl_xor(a0[d], ofs, 64);
        a1[d] += __shfl_xor(a1[d], ofs, 64);
      }

    if (lane == 0) {
      int i0 = 0, i1 = 0;
#pragma unroll
      for (int d = 0; d < CD; ++d) {
        const float h0 = a0[d] + bb[d];
        const float h1 = a1[d] + bb[d];
        h[(size_t)row0 * CD + d]       = h0;
        h[(size_t)(row0 + 1) * CD + d] = h1;
        i0 |= (h0 > 0.f) ? (1 << d) : 0;
        i1 |= (h1 > 0.f) ? (1 << d) : 0;
      }
      oidx[row0]     = (float)i0;
      oidx[row0 + 1] = (float)i1;
    }
  }
}

// ---------- Kernel B: fused out-projection + entropy/commit + histogram ----------
// 512 threads, 32 rows per block. Phase 0: q once -> LDS. Then ONE per-row loop
// doing out-write AND hist accumulation (mixes store-bound + VALU-bound work;
// single barrier). Tail: plain scal_part stores (no atomics, no pre-zero).
__global__ __launch_bounds__(512) void k_body(
    const float* __restrict__ h, const float* __restrict__ Wout,
    const float* __restrict__ bout, const float* __restrict__ oidx,
    float* __restrict__ out, float* __restrict__ hist_part,
    float* __restrict__ scal_part)
{
  __shared__ __align__(16) float sq[32 * 16];    // q[row][d], row-padded to 16
  __shared__ float pp[8], cc[8];
  const int t    = threadIdx.x;          // 0..511
  const int bid  = blockIdx.x;
  const int row0 = bid * 32;

  // ---------------- Phase 0: q-tree once per block ----------------
  if (t < 384) {                          // waves 0..5, one (row,d) per thread
    const float hv  = h[(size_t)row0 * CD + t];   // coalesced 384 floats
    const float ax  = fabsf(40.f * hv);
    const float e2  = __expf(-ax);
    const float s1  = 1.f + e2;
    const float inv = 1.f / s1;
    const float qv  = (hv > 0.f) ? inv : e2 * inv;          // sigmoid(40 h)
    sq[(t / 12) * 16 + (t % 12)] = qv;
    float pse_c = __logf(s1) + ax * e2 * inv;               // per-dim entropy
    const float dd = fabsf(hv) - 1.f;
    float com_c = dd * dd;
#pragma unroll
    for (int ofs = 1; ofs < 64; ofs <<= 1) {
      pse_c += __shfl_xor(pse_c, ofs, 64);
      com_c += __shfl_xor(com_c, ofs, 64);
    }
    if ((t & 63) == 0) { pp[t >> 6] = pse_c; cc[t >> 6] = com_c; }
  }

  // W_out fragment + bias for phase A part of the fused loop
  float w0[CD], w1[CD];
#pragma unroll
  for (int d = 0; d < CD; ++d) {
    float2 v = *reinterpret_cast<const float2*>(Wout + d * DIMX + 2 * t);
    w0[d] = v.x; w1[d] = v.y;
  }
  const float2 b2 = *reinterpret_cast<const float2*>(bout + 2 * t);

  __syncthreads();                        // sq + pp/cc ready

  // ---------------- Fused per-row loop: out-write + histogram ----------------
  const int lane = t & 63;
  const int w8   = t >> 6;                // wave id 0..7; m in [8*w8, 8*w8+8)

  float c0=0.f,c1=0.f,c2=0.f,c3=0.f,c4=0.f,c5=0.f,c6=0.f,c7=0.f;

  for (int i = 0; i < 32; ++i) {
    const int row = row0 + i;

    // --- out row (store-bound) ---
    const int idx = (int)oidx[row];       // block-uniform scalar load
    float o0 = b2.x, o1 = b2.y;
#pragma unroll
    for (int d = 0; d < CD; ++d) {
      const float s = ((idx >> d) & 1) ? 1.f : -1.f;
      o0 = fmaf(s, w0[d], o0);
      o1 = fmaf(s, w1[d], o1);
    }
    *reinterpret_cast<float2*>(out + (size_t)row * DIMX + 2 * t) = make_float2(o0, o1);

    // --- histogram (VALU-bound, overlaps the store) ---
    const float4 qa = *reinterpret_cast<const float4*>(&sq[i * 16]);      // q0..q3
    const float4 qb = *reinterpret_cast<const float4*>(&sq[i * 16 + 4]);  // q4..q7
    const float4 qc = *reinterpret_cast<const float4*>(&sq[i * 16 + 8]);  // q8..q11

    float A = ((lane >> 0) & 1) ? qa.x : 1.f - qa.x;
    A      *= ((lane >> 1) & 1) ? qa.y : 1.f - qa.y;
    A      *= ((lane >> 2) & 1) ? qa.z : 1.f - qa.z;
    A      *= ((lane >> 3) & 1) ? qa.w : 1.f - qa.w;
    A      *= ((lane >> 4) & 1) ? qb.x : 1.f - qb.x;
    A      *= ((lane >> 5) & 1) ? qb.y : 1.f - qb.y;

    const float t6 = 1.f - qb.z, t7 = 1.f - qb.w, t8 = 1.f - qc.x;
    const float u0 = t6 * t7, u1 = qb.z * t7, u2 = t6 * qb.w, u3 = qb.z * qb.w;
    const float E0 = A * (u0 * t8),   E1 = A * (u1 * t8),   E2 = A * (u2 * t8),   E3 = A * (u3 * t8);
    const float E4 = A * (u0 * qc.x), E5 = A * (u1 * qc.x), E6 = A * (u2 * qc.x), E7 = A * (u3 * qc.x);

    const float vw = (((w8 & 1) ? qc.y : 1.f - qc.y) * ((w8 & 2) ? qc.z : 1.f - qc.z));
    const float Dw = vw * ((w8 & 4) ? qc.w : 1.f - qc.w);

    c0 = fmaf(E0, Dw, c0); c1 = fmaf(E1, Dw, c1); c2 = fmaf(E2, Dw, c2); c3 = fmaf(E3, Dw, c3);
    c4 = fmaf(E4, Dw, c4); c5 = fmaf(E5, Dw, c5); c6 = fmaf(E6, Dw, c6); c7 = fmaf(E7, Dw, c7);
  }

  // disjoint coalesced slab write: index = (8*w8 + e)*64 + lane
  float* hp = hist_part + (size_t)bid * KCB + (size_t)w8 * 512 + lane;
  hp[0*64] = c0; hp[1*64] = c1; hp[2*64] = c2; hp[3*64] = c3;
  hp[4*64] = c4; hp[5*64] = c5; hp[6*64] = c6; hp[7*64] = c7;

  // tail: plain per-block partial stores (no atomics, nothing pre-zeroed)
  if (t == 0) {
    scal_part[bid * 2]     = pp[0] + pp[1] + pp[2] + pp[3] + pp[4] + pp[5];
    scal_part[bid * 2 + 1] = cc[0] + cc[1] + cc[2] + cc[3] + cc[4] + cc[5];
  }
}

// ---------- Kernel C: stage-1 slab reduction (128 blocks) ----------
__global__ __launch_bounds__(256) void k_hr1(
    const float* __restrict__ hist_part, float* __restrict__ part2)
{
  const int j0    = (blockIdx.x & 7) * 512 + threadIdx.x;
  const int chunk = blockIdx.x >> 3;              // 0..15
  const int s0    = chunk * (NSLAB / 16);
  float acc0 = 0.f, acc1 = 0.f;
#pragma unroll 4
  for (int s = 0; s < NSLAB / 16; ++s) {
    const float* hp = hist_part + (size_t)(s0 + s) * KCB;
    acc0 += hp[j0];
    acc1 += hp[j0 + 256];
  }
  part2[(size_t)chunk * KCB + j0]       = acc0;
  part2[(size_t)chunk * KCB + j0 + 256] = acc1;
}

// ---------- Kernel D: final entropy + scalar partials -> aux (1 block) ----------
__global__ __launch_bounds__(256) void k_fin(
    const float* __restrict__ part2, const float* __restrict__ scal_part,
    float* __restrict__ aux)
{
  const int t = threadIdx.x;
  float term = 0.f;
#pragma unroll
  for (int k = 0; k < 16; ++k) {
    const int j = t + 256 * k;
    float a = 0.f;
#pragma unroll
    for (int c = 0; c < 16; ++c) a += part2[(size_t)c * KCB + j];
    a *= (1.f / 16384.f);
    term -= a * __logf(a + 1e-10f);
  }
  // pse/com partials: 512 blocks x {pse, com}
  const float2 s0 = *reinterpret_cast<const float2*>(&scal_part[2 * t]);
  const float2 s1 = *reinterpret_cast<const float2*>(&scal_part[2 * (t + 256)]);
  float ps = s0.x + s1.x;
  float cs = s0.y + s1.y;
#pragma unroll
  for (int ofs = 1; ofs < 64; ofs <<= 1) {
    term += __shfl_xor(term, ofs, 64);
    ps   += __shfl_xor(ps,   ofs, 64);
    cs   += __shfl_xor(cs,   ofs, 64);
  }
  __shared__ float sw[4], sp[4], sc[4];
  if ((t & 63) == 0) { sw[t >> 6] = term; sp[t >> 6] = ps; sc[t >> 6] = cs; }
  __syncthreads();
  if (t == 0) {
    const float cbe = sw[0] + sw[1] + sw[2] + sw[3];
    const float PS  = sp[0] + sp[1] + sp[2] + sp[3];
    const float CS  = sc[0] + sc[1] + sc[2] + sc[3];
    aux[0] = PS * (1.f / 16384.f) - cbe + CS * (1.f / 196608.f);
  }
}

extern "C" void kernel_launch(void* const* d_in, const int* in_sizes, int n_in,
                              void* d_out, int out_size, void* d_ws, size_t ws_size,
                              hipStream_t stream)
{
  const float* x    = (const float*)d_in[0];
  const float* Win  = (const float*)d_in[1];
  const float* bin  = (const float*)d_in[2];
  const float* Wout = (const float*)d_in[3];
  const float* bout = (const float*)d_in[4];

  float* out  = (float*)d_out;                       // [16384 x 1024]
  float* oidx = out + (size_t)M_ROWS * DIMX;         // [16384]
  float* aux  = oidx + M_ROWS;                       // [1]

  float* ws        = (float*)d_ws;
  float* h         = ws;                             // 196608 floats
  float* scal_part = ws + (size_t)M_ROWS * CD;       // 1024 floats
  float* part2     = scal_part + 1024;               // 16 * 4096 floats
  float* hist_part = part2 + 16 * KCB;               // NSLAB * 4096 floats

  k_hproj<<<256, 512, 0, stream>>>(x, Win, bin, h, oidx);
  k_body <<<NSLAB, 512, 0, stream>>>(h, Wout, bout, oidx, out, hist_part, scal_part);
  k_hr1  <<<128, 256, 0, stream>>>(hist_part, part2);
  k_fin  <<<1, 256, 0, stream>>>(part2, scal_part, aux);
}

// Round 16
// 59.868 us; speedup vs baseline: 1.8775x; 1.0487x over previous
//
#include <hip/hip_runtime.h>

#define M_ROWS 16384
#define DIMX   1024
#define CD     12
#define KCB    4096
#define PADW   52   // 48 data + 4 pad dwords: 53.25 KB LDS; 3 blocks/CU even at
                    // 512 threads. Stride 52 dwords => conflict-free b128 reads.
#define NSLAB  512  // one hist slab per k_body block

// ---------- Kernel A: h = x @ W_in + b_in ; writes h and oidx ----------
// 512 threads / 8 waves, 3 blocks/CU (24 waves/CU). Per-row arithmetic (FMA
// order k,e,d; butterfly ofs 1..32; +bin at end) bit-identical to round-1..15
// => exact index match.
__global__ __launch_bounds__(512) void k_hproj(
    const float* __restrict__ x, const float* __restrict__ Win,
    const float* __restrict__ bin, float* __restrict__ h, float* __restrict__ oidx)
{
  __shared__ __align__(16) float w[256 * PADW];   // 53.25 KB
  for (int f = threadIdx.x; f < 256 * 12; f += 512) {
    const int P = f / 12, c = f % 12;
    float4 v = reinterpret_cast<const float4*>(Win)[f];
    *reinterpret_cast<float4*>(&w[P * PADW + 4 * c]) = v;
  }
  __syncthreads();

  const int wave = threadIdx.x >> 6;              // 0..7
  const int lane = threadIdx.x & 63;
  const int g    = blockIdx.x * 8 + wave;         // 8 rows per wave

  float bb[CD];
#pragma unroll
  for (int d = 0; d < CD; ++d) bb[d] = bin[d];

  for (int it = 0; it < 4; ++it) {                // 2 rows per iteration
    const int row0 = g * 8 + it * 2;
    const float4* xr0 = reinterpret_cast<const float4*>(x + (size_t)row0 * DIMX);
    const float4* xr1 = reinterpret_cast<const float4*>(x + (size_t)(row0 + 1) * DIMX);
    float a0[CD], a1[CD];
#pragma unroll
    for (int d = 0; d < CD; ++d) { a0[d] = 0.f; a1[d] = 0.f; }

#pragma unroll
    for (int k = 0; k < 4; ++k) {
      const int P = lane + 64 * k;
      float4 xv0 = xr0[P];
      float4 xv1 = xr1[P];
      const float4* wf = reinterpret_cast<const float4*>(&w[P * PADW]);
      float4 wq[12];
#pragma unroll
      for (int c = 0; c < 12; ++c) wq[c] = wf[c];
      const float* wfl = reinterpret_cast<const float*>(wq);
      float xe0[4] = {xv0.x, xv0.y, xv0.z, xv0.w};
      float xe1[4] = {xv1.x, xv1.y, xv1.z, xv1.w};
#pragma unroll
      for (int e = 0; e < 4; ++e)
#pragma unroll
        for (int d = 0; d < CD; ++d) {
          const float wv = wfl[e * CD + d];
          a0[d] = fmaf(xe0[e], wv, a0[d]);
          a1[d] = fmaf(xe1[e], wv, a1[d]);
        }
    }
#pragma unroll
    for (int ofs = 1; ofs < 64; ofs <<= 1)
#pragma unroll
      for (int d = 0; d < CD; ++d) {
        a0[d] += __shfl_xor(a0[d], ofs, 64);
        a1[d] += __shfl_xor(a1[d], ofs, 64);
      }

    if (lane == 0) {
      int i0 = 0, i1 = 0;
#pragma unroll
      for (int d = 0; d < CD; ++d) {
        const float h0 = a0[d] + bb[d];
        const float h1 = a1[d] + bb[d];
        h[(size_t)row0 * CD + d]       = h0;
        h[(size_t)(row0 + 1) * CD + d] = h1;
        i0 |= (h0 > 0.f) ? (1 << d) : 0;
        i1 |= (h1 > 0.f) ? (1 << d) : 0;
      }
      oidx[row0]     = (float)i0;
      oidx[row0 + 1] = (float)i1;
    }
  }
}

// ---------- Kernel B: fused out-projection + entropy/commit + histogram ----------
// 512 threads, 32 rows per block. Phase 0: q once -> LDS. Fused per-row loop.
// Round-16 change: signs derived from q in LDS (q_d > 0.5 <=> h_d > 0, exact
// incl. h=0) — deletes the 32-deep block-uniform oidx scalar-load chain that
// serialized the loop. k_body no longer reads oidx at all.
__global__ __launch_bounds__(512) void k_body(
    const float* __restrict__ h, const float* __restrict__ Wout,
    const float* __restrict__ bout, float* __restrict__ out,
    float* __restrict__ hist_part, float* __restrict__ scal_part)
{
  __shared__ __align__(16) float sq[32 * 16];    // q[row][d], row-padded to 16
  __shared__ float pp[8], cc[8];
  const int t    = threadIdx.x;          // 0..511
  const int bid  = blockIdx.x;
  const int row0 = bid * 32;

  // ---------------- Phase 0: q-tree once per block ----------------
  if (t < 384) {                          // waves 0..5, one (row,d) per thread
    const float hv  = h[(size_t)row0 * CD + t];   // coalesced 384 floats
    const float ax  = fabsf(40.f * hv);
    const float e2  = __expf(-ax);
    const float s1  = 1.f + e2;
    const float inv = 1.f / s1;
    const float qv  = (hv > 0.f) ? inv : e2 * inv;          // sigmoid(40 h)
    sq[(t / 12) * 16 + (t % 12)] = qv;
    float pse_c = __logf(s1) + ax * e2 * inv;               // per-dim entropy
    const float dd = fabsf(hv) - 1.f;
    float com_c = dd * dd;
#pragma unroll
    for (int ofs = 1; ofs < 64; ofs <<= 1) {
      pse_c += __shfl_xor(pse_c, ofs, 64);
      com_c += __shfl_xor(com_c, ofs, 64);
    }
    if ((t & 63) == 0) { pp[t >> 6] = pse_c; cc[t >> 6] = com_c; }
  }

  // W_out fragment + bias
  float w0[CD], w1[CD];
#pragma unroll
  for (int d = 0; d < CD; ++d) {
    float2 v = *reinterpret_cast<const float2*>(Wout + d * DIMX + 2 * t);
    w0[d] = v.x; w1[d] = v.y;
  }
  const float2 b2 = *reinterpret_cast<const float2*>(bout + 2 * t);

  __syncthreads();                        // sq + pp/cc ready

  // ---------------- Fused per-row loop: out-write + histogram ----------------
  const int lane = t & 63;
  const int w8   = t >> 6;                // wave id 0..7; m in [8*w8, 8*w8+8)

  float c0=0.f,c1=0.f,c2=0.f,c3=0.f,c4=0.f,c5=0.f,c6=0.f,c7=0.f;

  for (int i = 0; i < 32; ++i) {
    const int row = row0 + i;

    const float4 qa = *reinterpret_cast<const float4*>(&sq[i * 16]);      // q0..q3
    const float4 qb = *reinterpret_cast<const float4*>(&sq[i * 16 + 4]);  // q4..q7
    const float4 qc = *reinterpret_cast<const float4*>(&sq[i * 16 + 8]);  // q8..q11

    // --- out row: signs from q (q_d > 0.5 <=> h_d > 0) ---
    float o0 = b2.x, o1 = b2.y;
    {
      const float s0  = (qa.x > 0.5f) ? 1.f : -1.f;
      const float s1_ = (qa.y > 0.5f) ? 1.f : -1.f;
      const float s2  = (qa.z > 0.5f) ? 1.f : -1.f;
      const float s3  = (qa.w > 0.5f) ? 1.f : -1.f;
      const float s4  = (qb.x > 0.5f) ? 1.f : -1.f;
      const float s5  = (qb.y > 0.5f) ? 1.f : -1.f;
      const float s6  = (qb.z > 0.5f) ? 1.f : -1.f;
      const float s7  = (qb.w > 0.5f) ? 1.f : -1.f;
      const float s8  = (qc.x > 0.5f) ? 1.f : -1.f;
      const float s9  = (qc.y > 0.5f) ? 1.f : -1.f;
      const float s10 = (qc.z > 0.5f) ? 1.f : -1.f;
      const float s11 = (qc.w > 0.5f) ? 1.f : -1.f;
      o0 = fmaf(s0,  w0[0],  o0); o1 = fmaf(s0,  w1[0],  o1);
      o0 = fmaf(s1_, w0[1],  o0); o1 = fmaf(s1_, w1[1],  o1);
      o0 = fmaf(s2,  w0[2],  o0); o1 = fmaf(s2,  w1[2],  o1);
      o0 = fmaf(s3,  w0[3],  o0); o1 = fmaf(s3,  w1[3],  o1);
      o0 = fmaf(s4,  w0[4],  o0); o1 = fmaf(s4,  w1[4],  o1);
      o0 = fmaf(s5,  w0[5],  o0); o1 = fmaf(s5,  w1[5],  o1);
      o0 = fmaf(s6,  w0[6],  o0); o1 = fmaf(s6,  w1[6],  o1);
      o0 = fmaf(s7,  w0[7],  o0); o1 = fmaf(s7,  w1[7],  o1);
      o0 = fmaf(s8,  w0[8],  o0); o1 = fmaf(s8,  w1[8],  o1);
      o0 = fmaf(s9,  w0[9],  o0); o1 = fmaf(s9,  w1[9],  o1);
      o0 = fmaf(s10, w0[10], o0); o1 = fmaf(s10, w1[10], o1);
      o0 = fmaf(s11, w0[11], o0); o1 = fmaf(s11, w1[11], o1);
    }
    *reinterpret_cast<float2*>(out + (size_t)row * DIMX + 2 * t) = make_float2(o0, o1);

    // --- histogram (VALU-bound, overlaps the store) ---
    float A = ((lane >> 0) & 1) ? qa.x : 1.f - qa.x;
    A      *= ((lane >> 1) & 1) ? qa.y : 1.f - qa.y;
    A      *= ((lane >> 2) & 1) ? qa.z : 1.f - qa.z;
    A      *= ((lane >> 3) & 1) ? qa.w : 1.f - qa.w;
    A      *= ((lane >> 4) & 1) ? qb.x : 1.f - qb.x;
    A      *= ((lane >> 5) & 1) ? qb.y : 1.f - qb.y;

    const float t6 = 1.f - qb.z, t7 = 1.f - qb.w, t8 = 1.f - qc.x;
    const float u0 = t6 * t7, u1 = qb.z * t7, u2 = t6 * qb.w, u3 = qb.z * qb.w;
    const float E0 = A * (u0 * t8),   E1 = A * (u1 * t8),   E2 = A * (u2 * t8),   E3 = A * (u3 * t8);
    const float E4 = A * (u0 * qc.x), E5 = A * (u1 * qc.x), E6 = A * (u2 * qc.x), E7 = A * (u3 * qc.x);

    const float vw = (((w8 & 1) ? qc.y : 1.f - qc.y) * ((w8 & 2) ? qc.z : 1.f - qc.z));
    const float Dw = vw * ((w8 & 4) ? qc.w : 1.f - qc.w);

    c0 = fmaf(E0, Dw, c0); c1 = fmaf(E1, Dw, c1); c2 = fmaf(E2, Dw, c2); c3 = fmaf(E3, Dw, c3);
    c4 = fmaf(E4, Dw, c4); c5 = fmaf(E5, Dw, c5); c6 = fmaf(E6, Dw, c6); c7 = fmaf(E7, Dw, c7);
  }

  // disjoint coalesced slab write: index = (8*w8 + e)*64 + lane
  float* hp = hist_part + (size_t)bid * KCB + (size_t)w8 * 512 + lane;
  hp[0*64] = c0; hp[1*64] = c1; hp[2*64] = c2; hp[3*64] = c3;
  hp[4*64] = c4; hp[5*64] = c5; hp[6*64] = c6; hp[7*64] = c7;

  // tail: plain per-block partial stores (no atomics, nothing pre-zeroed)
  if (t == 0) {
    scal_part[bid * 2]     = pp[0] + pp[1] + pp[2] + pp[3] + pp[4] + pp[5];
    scal_part[bid * 2 + 1] = cc[0] + cc[1] + cc[2] + cc[3] + cc[4] + cc[5];
  }
}

// ---------- Kernel C: stage-1 slab reduction (128 blocks) ----------
__global__ __launch_bounds__(256) void k_hr1(
    const float* __restrict__ hist_part, float* __restrict__ part2)
{
  const int j0    = (blockIdx.x & 7) * 512 + threadIdx.x;
  const int chunk = blockIdx.x >> 3;              // 0..15
  const int s0    = chunk * (NSLAB / 16);
  float acc0 = 0.f, acc1 = 0.f;
#pragma unroll 4
  for (int s = 0; s < NSLAB / 16; ++s) {
    const float* hp = hist_part + (size_t)(s0 + s) * KCB;
    acc0 += hp[j0];
    acc1 += hp[j0 + 256];
  }
  part2[(size_t)chunk * KCB + j0]       = acc0;
  part2[(size_t)chunk * KCB + j0 + 256] = acc1;
}

// ---------- Kernel D: final entropy + scalar partials -> aux (1 block) ----------
__global__ __launch_bounds__(256) void k_fin(
    const float* __restrict__ part2, const float* __restrict__ scal_part,
    float* __restrict__ aux)
{
  const int t = threadIdx.x;
  float term = 0.f;
#pragma unroll
  for (int k = 0; k < 16; ++k) {
    const int j = t + 256 * k;
    float a = 0.f;
#pragma unroll
    for (int c = 0; c < 16; ++c) a += part2[(size_t)c * KCB + j];
    a *= (1.f / 16384.f);
    term -= a * __logf(a + 1e-10f);
  }
  // pse/com partials: 512 blocks x {pse, com}
  const float2 s0 = *reinterpret_cast<const float2*>(&scal_part[2 * t]);
  const float2 s1 = *reinterpret_cast<const float2*>(&scal_part[2 * (t + 256)]);
  float ps = s0.x + s1.x;
  float cs = s0.y + s1.y;
#pragma unroll
  for (int ofs = 1; ofs < 64; ofs <<= 1) {
    term += __shfl_xor(term, ofs, 64);
    ps   += __shfl_xor(ps,   ofs, 64);
    cs   += __shfl_xor(cs,   ofs, 64);
  }
  __shared__ float sw[4], sp[4], sc[4];
  if ((t & 63) == 0) { sw[t >> 6] = term; sp[t >> 6] = ps; sc[t >> 6] = cs; }
  __syncthreads();
  if (t == 0) {
    const float cbe = sw[0] + sw[1] + sw[2] + sw[3];
    const float PS  = sp[0] + sp[1] + sp[2] + sp[3];
    const float CS  = sc[0] + sc[1] + sc[2] + sc[3];
    aux[0] = PS * (1.f / 16384.f) - cbe + CS * (1.f / 196608.f);
  }
}

extern "C" void kernel_launch(void* const* d_in, const int* in_sizes, int n_in,
                              void* d_out, int out_size, void* d_ws, size_t ws_size,
                              hipStream_t stream)
{
  const float* x    = (const float*)d_in[0];
  const float* Win  = (const float*)d_in[1];
  const float* bin  = (const float*)d_in[2];
  const float* Wout = (const float*)d_in[3];
  const float* bout = (const float*)d_in[4];

  float* out  = (float*)d_out;                       // [16384 x 1024]
  float* oidx = out + (size_t)M_ROWS * DIMX;         // [16384]
  float* aux  = oidx + M_ROWS;                       // [1]

  float* ws        = (float*)d_ws;
  float* h         = ws;                             // 196608 floats
  float* scal_part = ws + (size_t)M_ROWS * CD;       // 1024 floats
  float* part2     = scal_part + 1024;               // 16 * 4096 floats
  float* hist_part = part2 + 16 * KCB;               // NSLAB * 4096 floats

  k_hproj<<<256, 512, 0, stream>>>(x, Win, bin, h, oidx);
  k_body <<<NSLAB, 512, 0, stream>>>(h, Wout, bout, out, hist_part, scal_part);
  k_hr1  <<<128, 256, 0, stream>>>(hist_part, part2);
  k_fin  <<<1, 256, 0, stream>>>(part2, scal_part, aux);
}

// Round 17
// 52.996 us; speedup vs baseline: 2.1210x; 1.1297x over previous
//
#include <hip/hip_runtime.h>

#define M_ROWS 16384
#define DIMX   1024
#define CD     12
#define KCB    4096
#define PADW   52   // 48 data + 4 pad dwords: 53.25 KB LDS; 3 blocks/CU even at
                    // 512 threads. Stride 52 dwords => conflict-free b128 reads.
#define NSLAB  512  // one hist slab per k_body block

// ---------- Kernel A: h = x @ W_in + b_in ; writes h and oidx ----------
// 512 threads / 8 waves. Round-17 change: FOLDED butterfly — 25 shuffles per
// 2-row pass instead of 144 (the shuffle ops share the LDS pipe with the b128
// W reads and were ~60% of its occupancy). The fold computes the SAME addition
// tree per value (a[l] + a[l^D], D = 1,2,4,8,16,32 in order) so h is
// bit-identical to rounds 1..16 => exact index match. Final layout: lane m
// (m<24) holds value m (m<12: row0 dim m; else row1 dim m-12) -> one coalesced
// 24-lane h store + one __ballot for both indices.
__global__ __launch_bounds__(512) void k_hproj(
    const float* __restrict__ x, const float* __restrict__ Win,
    const float* __restrict__ bin, float* __restrict__ h, float* __restrict__ oidx)
{
  __shared__ __align__(16) float w[256 * PADW];   // 53.25 KB
  for (int f = threadIdx.x; f < 256 * 12; f += 512) {
    const int P = f / 12, c = f % 12;
    float4 v4 = reinterpret_cast<const float4*>(Win)[f];
    *reinterpret_cast<float4*>(&w[P * PADW + 4 * c]) = v4;
  }
  __syncthreads();

  const int wave = threadIdx.x >> 6;              // 0..7
  const int lane = threadIdx.x & 63;
  const int g    = blockIdx.x * 8 + wave;         // 8 rows per wave

  // per-lane bin for the epilogue: lane m < 24 needs bin[m % 12]
  const float mybin = bin[lane < 12 ? lane : (lane < 24 ? lane - 12 : 0)];

  for (int it = 0; it < 4; ++it) {                // 2 rows per iteration
    const int row0 = g * 8 + it * 2;
    const float4* xr0 = reinterpret_cast<const float4*>(x + (size_t)row0 * DIMX);
    const float4* xr1 = reinterpret_cast<const float4*>(x + (size_t)(row0 + 1) * DIMX);
    float a0[CD], a1[CD];
#pragma unroll
    for (int d = 0; d < CD; ++d) { a0[d] = 0.f; a1[d] = 0.f; }

#pragma unroll
    for (int k = 0; k < 4; ++k) {
      const int P = lane + 64 * k;
      float4 xv0 = xr0[P];
      float4 xv1 = xr1[P];
      const float4* wf = reinterpret_cast<const float4*>(&w[P * PADW]);
      float4 wq[12];
#pragma unroll
      for (int c = 0; c < 12; ++c) wq[c] = wf[c];
      const float* wfl = reinterpret_cast<const float*>(wq);
      float xe0[4] = {xv0.x, xv0.y, xv0.z, xv0.w};
      float xe1[4] = {xv1.x, xv1.y, xv1.z, xv1.w};
#pragma unroll
      for (int e = 0; e < 4; ++e)
#pragma unroll
        for (int d = 0; d < CD; ++d) {
          const float wv = wfl[e * CD + d];
          a0[d] = fmaf(xe0[e], wv, a0[d]);
          a1[d] = fmaf(xe1[e], wv, a1[d]);
        }
    }

    // ---- folded butterfly (bit-identical tree to the plain xor-butterfly) ----
    float v[24];
#pragma unroll
    for (int d = 0; d < CD; ++d) { v[d] = a0[d]; v[12 + d] = a1[d]; }

    // stage 1 (ofs 1): 24 -> 12
#pragma unroll
    for (int i = 0; i < 12; ++i) {
      const float A = v[2 * i], B = v[2 * i + 1];
      const float keep = (lane & 1) ? B : A;
      const float give = (lane & 1) ? A : B;
      v[i] = keep + __shfl_xor(give, 1, 64);
    }
    // stage 2 (ofs 2): 12 -> 6
#pragma unroll
    for (int i = 0; i < 6; ++i) {
      const float A = v[2 * i], B = v[2 * i + 1];
      const float keep = (lane & 2) ? B : A;
      const float give = (lane & 2) ? A : B;
      v[i] = keep + __shfl_xor(give, 2, 64);
    }
    // stage 3 (ofs 4): 6 -> 3
#pragma unroll
    for (int i = 0; i < 3; ++i) {
      const float A = v[2 * i], B = v[2 * i + 1];
      const float keep = (lane & 4) ? B : A;
      const float give = (lane & 4) ? A : B;
      v[i] = keep + __shfl_xor(give, 4, 64);
    }
    // stage 4 (ofs 8): 3 -> 2 (fold v0,v1; v2 plain)
    {
      const float A = v[0], B = v[1];
      const float keep = (lane & 8) ? B : A;
      const float give = (lane & 8) ? A : B;
      v[0] = keep + __shfl_xor(give, 8, 64);
      v[1] = v[2] + __shfl_xor(v[2], 8, 64);
    }
    // stage 5 (ofs 16): 2 -> 1
    {
      const float A = v[0], B = v[1];
      const float keep = (lane & 16) ? B : A;
      const float give = (lane & 16) ? A : B;
      v[0] = keep + __shfl_xor(give, 16, 64);
    }
    // stage 6 (ofs 32): plain
    v[0] += __shfl_xor(v[0], 32, 64);

    // ---- epilogue: lane m (<24) holds value m ----
    const float hv = v[0] + mybin;
    const unsigned long long mask = __ballot(hv > 0.f);
    if (lane < 24) h[(size_t)row0 * CD + lane] = hv;
    if (lane == 0) {
      oidx[row0]     = (float)((int)(mask & 0xFFFULL));
      oidx[row0 + 1] = (float)((int)((mask >> 12) & 0xFFFULL));
    }
  }
}

// ---------- Kernel B: fused out-projection + entropy/commit + histogram ----------
// Round-16 proven version: 512 threads, 32 rows per block; q once -> LDS; one
// fused per-row loop (signs derived from q > 0.5); plain scal_part stores.
__global__ __launch_bounds__(512) void k_body(
    const float* __restrict__ h, const float* __restrict__ Wout,
    const float* __restrict__ bout, float* __restrict__ out,
    float* __restrict__ hist_part, float* __restrict__ scal_part)
{
  __shared__ __align__(16) float sq[32 * 16];    // q[row][d], row-padded to 16
  __shared__ float pp[8], cc[8];
  const int t    = threadIdx.x;          // 0..511
  const int bid  = blockIdx.x;
  const int row0 = bid * 32;

  // ---------------- Phase 0: q-tree once per block ----------------
  if (t < 384) {                          // waves 0..5, one (row,d) per thread
    const float hv  = h[(size_t)row0 * CD + t];   // coalesced 384 floats
    const float ax  = fabsf(40.f * hv);
    const float e2  = __expf(-ax);
    const float s1  = 1.f + e2;
    const float inv = 1.f / s1;
    const float qv  = (hv > 0.f) ? inv : e2 * inv;          // sigmoid(40 h)
    sq[(t / 12) * 16 + (t % 12)] = qv;
    float pse_c = __logf(s1) + ax * e2 * inv;               // per-dim entropy
    const float dd = fabsf(hv) - 1.f;
    float com_c = dd * dd;
#pragma unroll
    for (int ofs = 1; ofs < 64; ofs <<= 1) {
      pse_c += __shfl_xor(pse_c, ofs, 64);
      com_c += __shfl_xor(com_c, ofs, 64);
    }
    if ((t & 63) == 0) { pp[t >> 6] = pse_c; cc[t >> 6] = com_c; }
  }

  // W_out fragment + bias
  float w0[CD], w1[CD];
#pragma unroll
  for (int d = 0; d < CD; ++d) {
    float2 v = *reinterpret_cast<const float2*>(Wout + d * DIMX + 2 * t);
    w0[d] = v.x; w1[d] = v.y;
  }
  const float2 b2 = *reinterpret_cast<const float2*>(bout + 2 * t);

  __syncthreads();                        // sq + pp/cc ready

  // ---------------- Fused per-row loop: out-write + histogram ----------------
  const int lane = t & 63;
  const int w8   = t >> 6;                // wave id 0..7; m in [8*w8, 8*w8+8)

  float c0=0.f,c1=0.f,c2=0.f,c3=0.f,c4=0.f,c5=0.f,c6=0.f,c7=0.f;

  for (int i = 0; i < 32; ++i) {
    const int row = row0 + i;

    const float4 qa = *reinterpret_cast<const float4*>(&sq[i * 16]);      // q0..q3
    const float4 qb = *reinterpret_cast<const float4*>(&sq[i * 16 + 4]);  // q4..q7
    const float4 qc = *reinterpret_cast<const float4*>(&sq[i * 16 + 8]);  // q8..q11

    // --- out row: signs from q (q_d > 0.5 <=> h_d > 0) ---
    float o0 = b2.x, o1 = b2.y;
    {
      const float s0  = (qa.x > 0.5f) ? 1.f : -1.f;
      const float s1_ = (qa.y > 0.5f) ? 1.f : -1.f;
      const float s2  = (qa.z > 0.5f) ? 1.f : -1.f;
      const float s3  = (qa.w > 0.5f) ? 1.f : -1.f;
      const float s4  = (qb.x > 0.5f) ? 1.f : -1.f;
      const float s5  = (qb.y > 0.5f) ? 1.f : -1.f;
      const float s6  = (qb.z > 0.5f) ? 1.f : -1.f;
      const float s7  = (qb.w > 0.5f) ? 1.f : -1.f;
      const float s8  = (qc.x > 0.5f) ? 1.f : -1.f;
      const float s9  = (qc.y > 0.5f) ? 1.f : -1.f;
      const float s10 = (qc.z > 0.5f) ? 1.f : -1.f;
      const float s11 = (qc.w > 0.5f) ? 1.f : -1.f;
      o0 = fmaf(s0,  w0[0],  o0); o1 = fmaf(s0,  w1[0],  o1);
      o0 = fmaf(s1_, w0[1],  o0); o1 = fmaf(s1_, w1[1],  o1);
      o0 = fmaf(s2,  w0[2],  o0); o1 = fmaf(s2,  w1[2],  o1);
      o0 = fmaf(s3,  w0[3],  o0); o1 = fmaf(s3,  w1[3],  o1);
      o0 = fmaf(s4,  w0[4],  o0); o1 = fmaf(s4,  w1[4],  o1);
      o0 = fmaf(s5,  w0[5],  o0); o1 = fmaf(s5,  w1[5],  o1);
      o0 = fmaf(s6,  w0[6],  o0); o1 = fmaf(s6,  w1[6],  o1);
      o0 = fmaf(s7,  w0[7],  o0); o1 = fmaf(s7,  w1[7],  o1);
      o0 = fmaf(s8,  w0[8],  o0); o1 = fmaf(s8,  w1[8],  o1);
      o0 = fmaf(s9,  w0[9],  o0); o1 = fmaf(s9,  w1[9],  o1);
      o0 = fmaf(s10, w0[10], o0); o1 = fmaf(s10, w1[10], o1);
      o0 = fmaf(s11, w0[11], o0); o1 = fmaf(s11, w1[11], o1);
    }
    *reinterpret_cast<float2*>(out + (size_t)row * DIMX + 2 * t) = make_float2(o0, o1);

    // --- histogram (VALU-bound, overlaps the store) ---
    float A = ((lane >> 0) & 1) ? qa.x : 1.f - qa.x;
    A      *= ((lane >> 1) & 1) ? qa.y : 1.f - qa.y;
    A      *= ((lane >> 2) & 1) ? qa.z : 1.f - qa.z;
    A      *= ((lane >> 3) & 1) ? qa.w : 1.f - qa.w;
    A      *= ((lane >> 4) & 1) ? qb.x : 1.f - qb.x;
    A      *= ((lane >> 5) & 1) ? qb.y : 1.f - qb.y;

    const float t6 = 1.f - qb.z, t7 = 1.f - qb.w, t8 = 1.f - qc.x;
    const float u0 = t6 * t7, u1 = qb.z * t7, u2 = t6 * qb.w, u3 = qb.z * qb.w;
    const float E0 = A * (u0 * t8),   E1 = A * (u1 * t8),   E2 = A * (u2 * t8),   E3 = A * (u3 * t8);
    const float E4 = A * (u0 * qc.x), E5 = A * (u1 * qc.x), E6 = A * (u2 * qc.x), E7 = A * (u3 * qc.x);

    const float vw = (((w8 & 1) ? qc.y : 1.f - qc.y) * ((w8 & 2) ? qc.z : 1.f - qc.z));
    const float Dw = vw * ((w8 & 4) ? qc.w : 1.f - qc.w);

    c0 = fmaf(E0, Dw, c0); c1 = fmaf(E1, Dw, c1); c2 = fmaf(E2, Dw, c2); c3 = fmaf(E3, Dw, c3);
    c4 = fmaf(E4, Dw, c4); c5 = fmaf(E5, Dw, c5); c6 = fmaf(E6, Dw, c6); c7 = fmaf(E7, Dw, c7);
  }

  // disjoint coalesced slab write: index = (8*w8 + e)*64 + lane
  float* hp = hist_part + (size_t)bid * KCB + (size_t)w8 * 512 + lane;
  hp[0*64] = c0; hp[1*64] = c1; hp[2*64] = c2; hp[3*64] = c3;
  hp[4*64] = c4; hp[5*64] = c5; hp[6*64] = c6; hp[7*64] = c7;

  // tail: plain per-block partial stores (no atomics, nothing pre-zeroed)
  if (t == 0) {
    scal_part[bid * 2]     = pp[0] + pp[1] + pp[2] + pp[3] + pp[4] + pp[5];
    scal_part[bid * 2 + 1] = cc[0] + cc[1] + cc[2] + cc[3] + cc[4] + cc[5];
  }
}

// ---------- Kernel C: stage-1 slab reduction (128 blocks) ----------
__global__ __launch_bounds__(256) void k_hr1(
    const float* __restrict__ hist_part, float* __restrict__ part2)
{
  const int j0    = (blockIdx.x & 7) * 512 + threadIdx.x;
  const int chunk = blockIdx.x >> 3;              // 0..15
  const int s0    = chunk * (NSLAB / 16);
  float acc0 = 0.f, acc1 = 0.f;
#pragma unroll 4
  for (int s = 0; s < NSLAB / 16; ++s) {
    const float* hp = hist_part + (size_t)(s0 + s) * KCB;
    acc0 += hp[j0];
    acc1 += hp[j0 + 256];
  }
  part2[(size_t)chunk * KCB + j0]       = acc0;
  part2[(size_t)chunk * KCB + j0 + 256] = acc1;
}

// ---------- Kernel D: final entropy + scalar partials -> aux (1 block) ----------
__global__ __launch_bounds__(256) void k_fin(
    const float* __restrict__ part2, const float* __restrict__ scal_part,
    float* __restrict__ aux)
{
  const int t = threadIdx.x;
  float term = 0.f;
#pragma unroll
  for (int k = 0; k < 16; ++k) {
    const int j = t + 256 * k;
    float a = 0.f;
#pragma unroll
    for (int c = 0; c < 16; ++c) a += part2[(size_t)c * KCB + j];
    a *= (1.f / 16384.f);
    term -= a * __logf(a + 1e-10f);
  }
  // pse/com partials: 512 blocks x {pse, com}
  const float2 s0 = *reinterpret_cast<const float2*>(&scal_part[2 * t]);
  const float2 s1 = *reinterpret_cast<const float2*>(&scal_part[2 * (t + 256)]);
  float ps = s0.x + s1.x;
  float cs = s0.y + s1.y;
#pragma unroll
  for (int ofs = 1; ofs < 64; ofs <<= 1) {
    term += __shfl_xor(term, ofs, 64);
    ps   += __shfl_xor(ps,   ofs, 64);
    cs   += __shfl_xor(cs,   ofs, 64);
  }
  __shared__ float sw[4], sp[4], sc[4];
  if ((t & 63) == 0) { sw[t >> 6] = term; sp[t >> 6] = ps; sc[t >> 6] = cs; }
  __syncthreads();
  if (t == 0) {
    const float cbe = sw[0] + sw[1] + sw[2] + sw[3];
    const float PS  = sp[0] + sp[1] + sp[2] + sp[3];
    const float CS  = sc[0] + sc[1] + sc[2] + sc[3];
    aux[0] = PS * (1.f / 16384.f) - cbe + CS * (1.f / 196608.f);
  }
}

extern "C" void kernel_launch(void* const* d_in, const int* in_sizes, int n_in,
                              void* d_out, int out_size, void* d_ws, size_t ws_size,
                              hipStream_t stream)
{
  const float* x    = (const float*)d_in[0];
  const float* Win  = (const float*)d_in[1];
  const float* bin  = (const float*)d_in[2];
  const float* Wout = (const float*)d_in[3];
  const float* bout = (const float*)d_in[4];

  float* out  = (float*)d_out;                       // [16384 x 1024]
  float* oidx = out + (size_t)M_ROWS * DIMX;         // [16384]
  float* aux  = oidx + M_ROWS;                       // [1]

  float* ws        = (float*)d_ws;
  float* h         = ws;                             // 196608 floats
  float* scal_part = ws + (size_t)M_ROWS * CD;       // 1024 floats
  float* part2     = scal_part + 1024;               // 16 * 4096 floats
  float* hist_part = part2 + 16 * KCB;               // NSLAB * 4096 floats

  k_hproj<<<256, 512, 0, stream>>>(x, Win, bin, h, oidx);
  k_body <<<NSLAB, 512, 0, stream>>>(h, Wout, bout, out, hist_part, scal_part);
  k_hr1  <<<128, 256, 0, stream>>>(hist_part, part2);
  k_fin  <<<1, 256, 0, stream>>>(part2, scal_part, aux);
}